// Round 5
// baseline (423.216 us; speedup 1.0000x reference)
//
#include <hip/hip_runtime.h>
#include <math.h>

// Full-fidelity emulation of the reference as run by jax-rocm EAGERLY on this
// GPU (x64 on): all f64 transcendentals are __ocml_*_f64 == this kernel's
// exp()/log(). Both stages are inexact because jax lowers exp2(z) ->
// exp(RN(z*RN(ln2))) -- reproduced bit-for-bit.
//
// R5 changes (numerics bit-identical, structure-targeted):
//  * Persistent grid-stride kernel: 1024 blocks x ~4 tiles each. Tables are
//    built ONCE per block (4x fewer ocml-exp table builds and barriers than
//    R4's 4096 one-shot blocks); the steady-state loop has no barriers.
//  * Software pipeline across tiles: group-A loads of tile t+1 issue at loop
//    top (latency covered by tile t's decode+sigmoid), pack-A + group-B issue
//    mid-chain (covered by encode+store). A/B register buffers are never
//    simultaneously live -> peak ~90 VGPR, keeps 4 waves/SIMD.
//  * Wave-local dataflow unchanged from R4: value->lane map v = vbase +
//    (lane&7)*8 + (lane>>3); pack keeps own word (select i==lane&7), store
//    word fetched with one __shfl from lane (lane&56)+i. No LDS data path.
//  * Encode shortcuts unchanged from R3/R4 (absmax==0 twice):
//    - mantissa!=0 -> floor(log(a)/LN2) == E exactly (emu err ~1e-13 vs
//      1.7e-7 distance to integer); subnormal -> clip == -126; mantissa==0
//      (exact pow2) -> rare verbatim ocml log() path.
//    - mant = M + e, |e| <~ 1e-8: for sc > ctz(M), floor(mant*Lm[sc]) ==
//      M>>sc exactly -> parity is bit sc of M; only sc <= ctz(M) (incl. the
//      pow2 M=0 "W-1 garbage" case) runs the original f64 mul+floor step.

#define LN2C 0x1.62e42fefa39efp-1  // RN(ln2), XLA's folded log(2)

typedef unsigned int u32x4 __attribute__((ext_vector_type(4)));

__device__ __forceinline__ void load_group(const u32x4* __restrict__ in,
                                           int cb, int n_chunks,
                                           u32x4 (&B)[8]) {
#pragma unroll
  for (int i = 0; i < 8; ++i) {
    int g = cb + i * 64;
    u32x4 b = {0u, 0u, 0u, 0u};
    if (g < n_chunks) b = __builtin_nontemporal_load(&in[g]);
    B[i] = b;
  }
}

__device__ __forceinline__ uint32_t pack_group(const u32x4 (&B)[8],
                                               int nibshift, int keep) {
  uint32_t w = 0;
#pragma unroll
  for (int i = 0; i < 8; ++i) {
    u32x4 b = B[i];
    uint32_t p = (((((b.x >> 23) & 1u) << 3) | (((b.y >> 23) & 1u) << 2) |
                   (((b.z >> 23) & 1u) << 1) | ((b.w >> 23) & 1u)))
                 << nibshift;
    p |= __shfl_xor(p, 1);
    p |= __shfl_xor(p, 2);
    p |= __shfl_xor(p, 4);
    if (keep == i) w = p;
  }
  return w;
}

__global__ __launch_bounds__(256) void spike_gelu_kernel(
    const u32x4* __restrict__ in, u32x4* __restrict__ out,
    int n_vals, int n_tiles) {
#pragma clang fp contract(off)
  const double LN2 = LN2C;
  // Tables (exact ocml-call replicas of the reference's constant arrays):
  __shared__ double Wdec[8];     // decode exponent weights exp2emu(7..0)
  __shared__ double Lms[23];     // ladder scales exp2emu(0..-22)
  __shared__ double E1t[256];    // ordered Wdec sum -> exp((e_c-127)*LN2)
  __shared__ double Vdec[23];    // decode fraction weights exp2emu(-1..-23)
  __shared__ double P2t[254];    // encode exp(-e0*LN2), e0 in [-126,127]
  __shared__ uint32_t etab[256]; // 8-step exponent floor-ladder per eb

  const int tid = threadIdx.x;
  const int lane = tid & 63;
  const int wid = tid >> 6;
  const int n_chunks = n_vals * 8;
  const int nibshift = 28 - 4 * (lane & 7);
  const int keep = lane & 7;
  const int tstep = gridDim.x;

  int tile = blockIdx.x;
  u32x4 A[8], Bb[8];

  // Tile t: values [t*512, t*512+512); wave's chunk base = t*4096+wid*1024+lane.
  load_group(in, tile * 4096 + wid * 1024 + lane, n_chunks, A);  // in flight

  // ---- table stage 1 ------------------------------------------------------
  if (tid < 8) Wdec[tid] = exp((double)(7 - tid) * LN2);
  if (tid >= 31 && tid < 54) Lms[tid - 31] = exp((double)(31 - tid) * LN2);
  __syncthreads();
  // ---- table stage 2 (reference op order) ---------------------------------
  if (tid == 0) {
    E1t[0] = exp(-126.0 * LN2);  // subnormal-branch scale (e_c==0)
  } else {
    double e_c = 0.0;
#pragma unroll
    for (int j = 0; j < 8; ++j)   // ascending-j einsum accumulation, verbatim
      if ((tid >> (7 - j)) & 1) e_c = e_c + Wdec[j];
    E1t[tid] = exp((e_c - 127.0) * LN2);
  }
  if (tid < 23) Vdec[tid] = exp((double)(-1 - tid) * LN2);
  if (tid < 254) P2t[tid] = exp((double)(126 - tid) * LN2);  // exp(-e0*LN2)
  if (tid >= 1 && tid < 255) {  // exponent-bit ladder, original formula
    double eb = (double)tid;
    uint32_t r = 0;
#pragma unroll
    for (int sc = 7; sc >= 0; --sc) {
      double f = floor(eb * Lms[sc]);
      double md = f - 2.0 * floor(0.5 * f);
      r |= ((uint32_t)md) << (23 + sc);
    }
    etab[tid] = r;
  } else {
    etab[tid] = 0u;  // hygiene, never read
  }
  __syncthreads();  // tables ready; no further block-wide coupling

  // ---- prologue: finish tile-0 staging ------------------------------------
  load_group(in, tile * 4096 + wid * 1024 + lane + 512, n_chunks, Bb);
  uint32_t w0 = pack_group(A, nibshift, keep);   // A complete (barrier drain)
  uint32_t w1 = pack_group(Bb, nibshift, keep);  // one exposed wait at start

  // ---- steady-state pipelined tile loop -----------------------------------
  for (;;) {
    const int ntile = tile + tstep;
    const bool havenext = ntile < n_tiles;
    const int ncb = ntile * 4096 + wid * 1024 + lane;
    if (havenext) load_group(in, ncb, n_chunks, A);  // covered by decode+exp

    const int vbase = tile * 512 + wid * 128;
    const int v0 = vbase + (lane & 7) * 8 + (lane >> 3);
    const int v1 = v0 + 64;
    const bool ok0 = v0 < n_vals, ok1 = v1 < n_vals;

    // DECODE (branchless, both chains interleaved)
    double f0 = 0.0, f1 = 0.0;
#pragma unroll
    for (int j = 0; j < 23; ++j) {
      double vj = Vdec[j];
      if ((w0 >> (22 - j)) & 1u) f0 = f0 + vj;
      if ((w1 >> (22 - j)) & 1u) f1 = f1 + vj;
    }
    uint32_t ei0 = (w0 >> 23) & 0xFFu, ei1 = (w1 >> 23) & 0xFFu;
    double sg0 = (w0 >> 31) ? -1.0 : 1.0, sg1 = (w1 >> 31) ? -1.0 : 1.0;
    double fa0 = ei0 ? (1.0 + f0) : f0, fa1 = ei1 ? (1.0 + f1) : f1;
    double x0 = (sg0 * E1t[ei0]) * fa0, x1 = (sg1 * E1t[ei1]) * fa1;

    // f64 GELU, exp-form logistic, ocml exp (two inlined bodies, adjacent)
    double t0 = 1.702 * x0, t1 = 1.702 * x1;
    double e0v = exp(-t0), e1v = exp(-t1);
    double s0 = 1.0 / (1.0 + e0v), s1 = 1.0 / (1.0 + e1v);
    double y0 = x0 * s0, y1 = x1 * s1;
    float yf0 = (float)y0, yf1 = (float)y1;
    double yd0 = (double)yf0, yd1 = (double)yf1;

    // mid-chain: A(next) has had the whole decode+exp to land; compress it
    // to one word and put B(next) in flight under encode+store.
    uint32_t nw0 = 0;
    if (havenext) {
      nw0 = pack_group(A, nibshift, keep);
      load_group(in, ncb + 512, n_chunks, Bb);
    }

    // ENCODE
    double a0 = fabs(yd0), a1 = fabs(yd1);
    uint32_t yb0 = __float_as_uint(yf0), yb1 = __float_as_uint(yf1);
    uint32_t Ef0 = (yb0 >> 23) & 0xFFu, Ef1 = (yb1 >> 23) & 0xFFu;
    uint32_t mbf0 = yb0 & 0x7FFFFFu, mbf1 = yb1 & 0x7FFFFFu;
    int e00 = (Ef0 == 0u) ? -126 : (int)Ef0 - 127;
    int e01 = (Ef1 == 0u) ? -126 : (int)Ef1 - 127;
    bool pw0 = ok0 && (a0 > 0.0) && (Ef0 != 0u) && (mbf0 == 0u);
    bool pw1 = ok1 && (a1 > 0.0) && (Ef1 != 0u) && (mbf1 == 0u);
    if (__builtin_expect(pw0 || pw1, 0)) {  // exact pow2: ocml log boundary
      if (pw0) {
        double e0 = floor(log(a0) / LN2);
        e00 = (int)fmin(fmax(e0, -126.0), 127.0);
      }
      if (pw1) {
        double e0 = floor(log(a1) / LN2);
        e01 = (int)fmin(fmax(e0, -126.0), 127.0);
      }
    }
    double p20 = P2t[e00 + 126], p21 = P2t[e01 + 126];
    double m10 = a0 * p20, m11 = a1 * p21;        // RN: may be W' +- eps
    double mant0 = (m10 - 1.0) * 8388608.0;       // Sterbenz-exact, exact scale
    double mant1 = (m11 - 1.0) * 8388608.0;
    int M0 = (int)rint(mant0), M1 = (int)rint(mant1);
    uint32_t mb0 = ((uint32_t)M0) & 0x7FFFFFu;
    uint32_t mb1 = ((uint32_t)M1) & 0x7FFFFFu;
    int T0 = M0 ? __builtin_ctz((uint32_t)M0) : 23;
    int T1 = M1 ? __builtin_ctz((uint32_t)M1) : 23;
    int L0 = T0 < 22 ? T0 : 22, L1 = T1 < 22 ? T1 : 22;
    int Lmax = L0 > L1 ? L0 : L1;
    for (int sc = 0; sc <= Lmax; ++sc) {          // boundary scs: original math
      double lm = Lms[sc];
      if (sc <= L0) {
        double f = floor(mant0 * lm);
        mb0 = (mb0 & ~(1u << sc)) | (((uint32_t)(((int)f) & 1)) << sc);
      }
      if (sc <= L1) {
        double f = floor(mant1 * lm);
        mb1 = (mb1 & ~(1u << sc)) | (((uint32_t)(((int)f) & 1)) << sc);
      }
    }
    uint32_t ob0 = (yb0 & 0x80000000u) | etab[e00 + 127] | mb0;
    uint32_t ob1 = (yb1 & 0x80000000u) | etab[e01 + 127] | mb1;
    ob0 = (ok0 && a0 > 0.0) ? ob0 : 0u;
    ob1 = (ok1 && a1 > 0.0) ? ob1 : 0u;

    // STORE (wave-local: word for chunk i from lane (lane&56)+i)
    const int ccb = tile * 4096 + wid * 1024 + lane;
#pragma unroll
    for (int i = 0; i < 8; ++i) {
      int g0 = ccb + i * 64;
      int g1 = g0 + 512;
      int src = (lane & 56) + i;
      uint32_t wa = __shfl(ob0, src);
      uint32_t wb = __shfl(ob1, src);
      int base = 31 - 4 * (lane & 7);
      if (g0 < n_chunks) {
        u32x4 o;
        o.x = ((wa >> base) & 1u) * 0x3F800000u;
        o.y = ((wa >> (base - 1)) & 1u) * 0x3F800000u;
        o.z = ((wa >> (base - 2)) & 1u) * 0x3F800000u;
        o.w = ((wa >> (base - 3)) & 1u) * 0x3F800000u;
        __builtin_nontemporal_store(o, &out[g0]);
      }
      if (g1 < n_chunks) {
        u32x4 o;
        o.x = ((wb >> base) & 1u) * 0x3F800000u;
        o.y = ((wb >> (base - 1)) & 1u) * 0x3F800000u;
        o.z = ((wb >> (base - 2)) & 1u) * 0x3F800000u;
        o.w = ((wb >> (base - 3)) & 1u) * 0x3F800000u;
        __builtin_nontemporal_store(o, &out[g1]);
      }
    }

    if (!havenext) break;
    uint32_t nw1 = pack_group(Bb, nibshift, keep);  // B(next): encode+store cover
    w0 = nw0;
    w1 = nw1;
    tile = ntile;
  }
}

extern "C" void kernel_launch(void* const* d_in, const int* in_sizes, int n_in,
                              void* d_out, int out_size, void* d_ws, size_t ws_size,
                              hipStream_t stream) {
  int n_vals = in_sizes[0] / 32;
  int n_tiles = (n_vals + 511) / 512;
  int grid = n_tiles < 1024 ? n_tiles : 1024;
  spike_gelu_kernel<<<grid, 256, 0, stream>>>(
      (const u32x4*)d_in[0], (u32x4*)d_out, n_vals, n_tiles);
}

// Round 6
// 418.898 us; speedup vs baseline: 1.0103x; 1.0103x over previous
//
#include <hip/hip_runtime.h>
#include <math.h>

// Full-fidelity emulation of the reference as run by jax-rocm EAGERLY on this
// GPU (x64 on): all f64 transcendentals are __ocml_*_f64 == this kernel's
// exp()/log(). Both stages are inexact because jax lowers exp2(z) ->
// exp(RN(z*RN(ln2))) -- reproduced bit-for-bit.
//
// R6 changes (numerics bit-identical, occupancy/TLP-targeted):
//  * R5 post-mortem: persistent+pipelined structure REGRESSED (+3.9us) --
//    mid-chain pack stalls + doubled live registers. Reverting to R4's
//    one-shot block structure (best measured) and pushing the other lever:
//    wave-level parallelism.
//  * 1 value/lane (was 2), single 32-VGPR load buffer (no A/B double
//    buffer): peak ~65 VGPR instead of ~110. __launch_bounds__(512, 6)
//    guarantees >=6 waves/SIMD (84-VGPR cap, comfortably above natural
//    usage -> no spill); natural allocation may reach 8/SIMD. R0 measured
//    67% occupancy at 4 waves/SIMD; the residual 35us over the 82us memory
//    floor is per-wave serial-chain latency exposure, which TLP hides.
//  * Block = 512 threads (8 waves), grid 4096. Table build split across all
//    8 waves (etab in the upper half); still hidden under in-flight loads.
//  * Wave-local dataflow unchanged from R4: value->lane map v = vwave +
//    (lane&7)*8 + (lane>>3); pack keeps own word (select i==lane&7); store
//    word via one __shfl from lane (lane&56)+i. No LDS data path.
//  * Encode shortcuts unchanged from R3/R4/R5 (absmax==0 three times):
//    - mantissa!=0 -> floor(log(a)/LN2) == E exactly (emu err ~1e-13 vs
//      1.7e-7 distance to integer); subnormal -> clip == -126; mantissa==0
//      (exact pow2) -> rare verbatim ocml log() path.
//    - mant = M + e, |e| <~ 1e-8: for sc > ctz(M), floor(mant*Lm[sc]) ==
//      M>>sc exactly -> parity is bit sc of M; only sc <= ctz(M) (incl. the
//      pow2 M=0 "W-1 garbage" case) runs the original f64 mul+floor step.

#define LN2C 0x1.62e42fefa39efp-1  // RN(ln2), XLA's folded log(2)

typedef unsigned int u32x4 __attribute__((ext_vector_type(4)));

__global__ __launch_bounds__(512, 6) void spike_gelu_kernel(
    const u32x4* __restrict__ in, u32x4* __restrict__ out, int n_vals) {
#pragma clang fp contract(off)
  const double LN2 = LN2C;
  // Tables (exact ocml-call replicas of the reference's constant arrays):
  __shared__ double Wdec[8];     // decode exponent weights exp2emu(7..0)
  __shared__ double Lms[23];     // ladder scales exp2emu(0..-22)
  __shared__ double E1t[256];    // ordered Wdec sum -> exp((e_c-127)*LN2)
  __shared__ double Vdec[23];    // decode fraction weights exp2emu(-1..-23)
  __shared__ double P2t[254];    // encode exp(-e0*LN2), e0 in [-126,127]
  __shared__ uint32_t etab[256]; // 8-step exponent floor-ladder per eb

  const int tid = threadIdx.x;
  const int lane = tid & 63;
  const int wid = tid >> 6;  // 0..7
  const int n_chunks = n_vals * 8;

  // Wave owns 64 values; its 512 chunks start at cbase.
  const int vwave = blockIdx.x * 512 + wid * 64;
  const int cbase = vwave * 8 + lane;

  // ---- issue loads first (8 x 16B in flight under the table build) --------
  u32x4 A[8];
#pragma unroll
  for (int i = 0; i < 8; ++i) {
    int g = cbase + i * 64;
    u32x4 b = {0u, 0u, 0u, 0u};
    if (g < n_chunks) b = __builtin_nontemporal_load(&in[g]);
    A[i] = b;
  }

  // ---- table stage 1 ------------------------------------------------------
  if (tid < 8) Wdec[tid] = exp((double)(7 - tid) * LN2);
  if (tid >= 31 && tid < 54) Lms[tid - 31] = exp((double)(31 - tid) * LN2);
  __syncthreads();
  // ---- table stage 2 (reference op order; split across all 8 waves) -------
  if (tid == 0) {
    E1t[0] = exp(-126.0 * LN2);  // subnormal-branch scale (e_c==0)
  } else if (tid < 256) {
    double e_c = 0.0;
#pragma unroll
    for (int j = 0; j < 8; ++j)   // ascending-j einsum accumulation, verbatim
      if ((tid >> (7 - j)) & 1) e_c = e_c + Wdec[j];
    E1t[tid] = exp((e_c - 127.0) * LN2);
  }
  if (tid < 23) Vdec[tid] = exp((double)(-1 - tid) * LN2);
  if (tid < 254) P2t[tid] = exp((double)(126 - tid) * LN2);  // exp(-e0*LN2)
  if (tid >= 256) {  // upper 4 waves: exponent-bit ladder, original formula
    const int tt = tid - 256;
    if (tt >= 1 && tt < 255) {
      double eb = (double)tt;
      uint32_t r = 0;
#pragma unroll
      for (int sc = 7; sc >= 0; --sc) {
        double f = floor(eb * Lms[sc]);
        double md = f - 2.0 * floor(0.5 * f);
        r |= ((uint32_t)md) << (23 + sc);
      }
      etab[tt] = r;
    } else {
      etab[tt] = 0u;  // hygiene, never read
    }
  }
  __syncthreads();  // tables ready; no further block-wide coupling

  // ---- pack: wave-local bit transpose -------------------------------------
  // Chunk cbase+i*64+lane holds value vwave+i*8+(lane>>3), nibble pos lane&7.
  // After the 3 xor-ors all 8 lanes of a group hold that value's word; lane
  // keeps its own value (v = vwave + (lane&7)*8 + (lane>>3)) at i == lane&7.
  const int nibshift = 28 - 4 * (lane & 7);
  const int keep = lane & 7;
  uint32_t w0 = 0u;
#pragma unroll
  for (int i = 0; i < 8; ++i) {
    u32x4 b = A[i];
    uint32_t p = (((((b.x >> 23) & 1u) << 3) | (((b.y >> 23) & 1u) << 2) |
                   (((b.z >> 23) & 1u) << 1) | ((b.w >> 23) & 1u)))
                 << nibshift;
    p |= __shfl_xor(p, 1);
    p |= __shfl_xor(p, 2);
    p |= __shfl_xor(p, 4);
    if (keep == i) w0 = p;
  }

  // ---- per-value chain (bit-identical to R4's chain 0) --------------------
  const int v0 = vwave + (lane & 7) * 8 + (lane >> 3);
  const bool ok0 = v0 < n_vals;

  // DECODE
  double f0 = 0.0;
#pragma unroll
  for (int j = 0; j < 23; ++j)
    if ((w0 >> (22 - j)) & 1u) f0 = f0 + Vdec[j];
  uint32_t ei0 = (w0 >> 23) & 0xFFu;
  double sg0 = (w0 >> 31) ? -1.0 : 1.0;
  double fa0 = ei0 ? (1.0 + f0) : f0;
  double x0 = (sg0 * E1t[ei0]) * fa0;

  // f64 GELU, exp-form logistic, ocml exp
  double t0 = 1.702 * x0;
  double e0v = exp(-t0);
  double s0 = 1.0 / (1.0 + e0v);
  double y0 = x0 * s0;
  float yf0 = (float)y0;   // astype(float32): RN
  double yd0 = (double)yf0;

  // ENCODE
  double a0 = fabs(yd0);
  uint32_t yb0 = __float_as_uint(yf0);
  uint32_t Ef0 = (yb0 >> 23) & 0xFFu;
  uint32_t mbf0 = yb0 & 0x7FFFFFu;
  int e00 = (Ef0 == 0u) ? -126 : (int)Ef0 - 127;
  bool pw0 = ok0 && (a0 > 0.0) && (Ef0 != 0u) && (mbf0 == 0u);
  if (__builtin_expect(pw0, 0)) {  // exact pow2: ocml log boundary, verbatim
    double e0 = floor(log(a0) / LN2);
    e00 = (int)fmin(fmax(e0, -126.0), 127.0);
  }
  double p20 = P2t[e00 + 126];
  double m10 = a0 * p20;               // RN: may be W' +- eps
  double mant0 = (m10 - 1.0) * 8388608.0;  // Sterbenz-exact, exact scale
  int M0 = (int)rint(mant0);
  uint32_t mb0 = ((uint32_t)M0) & 0x7FFFFFu;
  int T0 = M0 ? __builtin_ctz((uint32_t)M0) : 23;
  int L0 = T0 < 22 ? T0 : 22;
  for (int sc = 0; sc <= L0; ++sc) {   // boundary scs: original f64 math
    double f = floor(mant0 * Lms[sc]);
    mb0 = (mb0 & ~(1u << sc)) | (((uint32_t)(((int)f) & 1)) << sc);
  }
  uint32_t ob0 = (yb0 & 0x80000000u) | etab[e00 + 127] | mb0;
  ob0 = (ok0 && a0 > 0.0) ? ob0 : 0u;

  // ---- store: wave-local pulse expansion ----------------------------------
  // Chunk cbase+i*64 needs value vwave+i*8+(lane>>3), held at lane
  // (lane&56)+i under the map above. Issue all 8 bpermutes, then expand.
  uint32_t wv[8];
#pragma unroll
  for (int i = 0; i < 8; ++i) wv[i] = __shfl(ob0, (lane & 56) + i);
  const int base = 31 - 4 * (lane & 7);
#pragma unroll
  for (int i = 0; i < 8; ++i) {
    int g = cbase + i * 64;
    if (g < n_chunks) {
      uint32_t wa = wv[i];
      u32x4 o;
      o.x = ((wa >> base) & 1u) * 0x3F800000u;
      o.y = ((wa >> (base - 1)) & 1u) * 0x3F800000u;
      o.z = ((wa >> (base - 2)) & 1u) * 0x3F800000u;
      o.w = ((wa >> (base - 3)) & 1u) * 0x3F800000u;
      __builtin_nontemporal_store(o, &out[g]);
    }
  }
}

extern "C" void kernel_launch(void* const* d_in, const int* in_sizes, int n_in,
                              void* d_out, int out_size, void* d_ws, size_t ws_size,
                              hipStream_t stream) {
  int n_vals = in_sizes[0] / 32;
  int grid = (n_vals + 511) / 512;
  spike_gelu_kernel<<<grid, 512, 0, stream>>>(
      (const u32x4*)d_in[0], (u32x4*)d_out, n_vals);
}